// Round 1
// baseline (1317.500 us; speedup 1.0000x reference)
//
#include <hip/hip_runtime.h>

#define NN 100000
#define NE 1600000
#define NTILE_E (NE / 128)      // 12500, exact
#define NTILE_N 782             // ceil(100000/128)

typedef __attribute__((ext_vector_type(4))) float f32x4;
typedef __attribute__((ext_vector_type(8))) short s16x8;

__device__ __forceinline__ unsigned short f2bf(float f) {
  unsigned u = __builtin_bit_cast(unsigned, f);
  u = (u + 0x7FFFu + ((u >> 16) & 1u)) >> 16;
  return (unsigned short)u;
}
__device__ __forceinline__ void pack4(float4 v, unsigned short* dst) {
  ushort4 h;
  h.x = f2bf(v.x); h.y = f2bf(v.y); h.z = f2bf(v.z); h.w = f2bf(v.w);
  *(ushort4*)dst = h;
}

// ---------------------------------------------------------------- K0: weight prep
// W1 [128k][128n] f32 -> W1bT [n][k] bf16 ; W3 [192k][128n] f32 -> W3bT [n][192k] bf16
__global__ void k0_prep(const float* __restrict__ W1, const float* __restrict__ W3,
                        unsigned short* __restrict__ W1bT, unsigned short* __restrict__ W3bT) {
  int i = blockIdx.x * 256 + threadIdx.x;
  if (i < 16384) {
    int n = i >> 7, k = i & 127;
    W1bT[i] = f2bf(W1[k * 128 + n]);
  } else if (i < 16384 + 24576) {
    int j = i - 16384;
    int n = j / 192, k = j % 192;
    W3bT[j] = f2bf(W3[k * 128 + n]);
  }
}

// ---------------------------------------------------------------- K1: edge pass
// h1 = leaky(concat(x[row], ea) @ W1 + b1); scatter-add h1 into S[col]; BN1 stats; cnt hist
__global__ __launch_bounds__(256, 2) void k1_edge(
    const float* __restrict__ x, const int* __restrict__ eidx,
    const float* __restrict__ ea, const unsigned short* __restrict__ W1bT,
    const float* __restrict__ b1,
    float* __restrict__ S, float* __restrict__ cnt, float* __restrict__ stat1) {
  __shared__ unsigned short At[128][136];   // 128 edges x 128 k, bf16, +8 pad
  __shared__ int rIdx[128];
  __shared__ int cIdx[128];
  __shared__ float sred[256];

  const int tid = threadIdx.x;
  const int wave = tid >> 6, lane = tid & 63;
  const int l15 = lane & 15, quad = lane >> 4;
  const int rowbase = (wave >> 1) * 64;   // 0 / 64
  const int colbase = (wave & 1) * 64;    // 0 / 64

  // B fragments (W1) held in registers for the whole kernel: 16 frags = 64 VGPR
  s16x8 bfrag[4][4];
#pragma unroll
  for (int ct = 0; ct < 4; ct++)
#pragma unroll
    for (int ks = 0; ks < 4; ks++)
      bfrag[ct][ks] = *(const s16x8*)(W1bT + (colbase + ct * 16 + l15) * 128 + ks * 32 + quad * 8);

  float b1j[4];
#pragma unroll
  for (int ct = 0; ct < 4; ct++) b1j[ct] = b1[colbase + ct * 16 + l15];

  float lsum[4] = {0, 0, 0, 0}, lsq[4] = {0, 0, 0, 0};

  for (int tile = blockIdx.x; tile < NTILE_E; tile += gridDim.x) {
    const int eb = tile * 128;
    __syncthreads();   // protect LDS from previous iteration's readers
    if (tid < 128) { rIdx[tid] = eidx[eb + tid]; cIdx[tid] = eidx[NE + eb + tid]; }
    __syncthreads();
    // stage A tile: cols 0..63 = x[row] (gather), cols 64..127 = edge_attr (stream)
#pragma unroll
    for (int i = 0; i < 8; i++) {
      int idx = tid + i * 256; int e = idx >> 4, c = idx & 15;
      float4 v = ((const float4*)x)[(size_t)rIdx[e] * 16 + c];
      pack4(v, &At[e][c * 4]);
    }
#pragma unroll
    for (int i = 0; i < 8; i++) {
      int idx = tid + i * 256; int e = idx >> 4, c = idx & 15;
      float4 v = ((const float4*)ea)[(size_t)(eb + e) * 16 + c];
      pack4(v, &At[e][64 + c * 4]);
    }
    __syncthreads();
    if (tid < 128) atomicAdd(&cnt[cIdx[tid]], 1.0f);

    f32x4 acc[4][4];
#pragma unroll
    for (int rt = 0; rt < 4; rt++)
#pragma unroll
      for (int ct = 0; ct < 4; ct++) acc[rt][ct] = (f32x4){0.f, 0.f, 0.f, 0.f};

#pragma unroll
    for (int ks = 0; ks < 4; ks++) {
      s16x8 af[4];
#pragma unroll
      for (int rt = 0; rt < 4; rt++)
        af[rt] = *(const s16x8*)&At[rowbase + rt * 16 + l15][ks * 32 + quad * 8];
#pragma unroll
      for (int rt = 0; rt < 4; rt++)
#pragma unroll
        for (int ct = 0; ct < 4; ct++)
          acc[rt][ct] = __builtin_amdgcn_mfma_f32_16x16x32_bf16(af[rt], bfrag[ct][ks], acc[rt][ct], 0, 0, 0);
    }

    // epilogue: bias + leaky + stats + scatter-add raw h1 into S[col[e]]
#pragma unroll
    for (int rt = 0; rt < 4; rt++) {
#pragma unroll
      for (int r = 0; r < 4; r++) {
        const int er = rowbase + rt * 16 + quad * 4 + r;
        float* Srow = S + (size_t)cIdx[er] * 128;
#pragma unroll
        for (int ct = 0; ct < 4; ct++) {
          float v = acc[rt][ct][r] + b1j[ct];
          v = v > 0.0f ? v : 0.01f * v;
          lsum[ct] += v; lsq[ct] += v * v;
          atomicAdd(Srow + colbase + ct * 16 + l15, v);
        }
      }
    }
  }

  // block-level stat reduction, then one global atomic per channel-quantity
  sred[tid] = 0.0f;
  __syncthreads();
#pragma unroll
  for (int ct = 0; ct < 4; ct++) {
    float s = lsum[ct], q = lsq[ct];
    s += __shfl_down(s, 32); q += __shfl_down(q, 32);
    s += __shfl_down(s, 16); q += __shfl_down(q, 16);
    if (lane < 16) {
      atomicAdd(&sred[colbase + ct * 16 + l15], s);
      atomicAdd(&sred[128 + colbase + ct * 16 + l15], q);
    }
  }
  __syncthreads();
  atomicAdd(&stat1[tid], sred[tid]);
}

// ---------------------------------------------------------------- K2: fold BN1 into W2
__global__ void k2_fold1(const float* __restrict__ stat1, const float* __restrict__ g1,
                         const float* __restrict__ be1, const float* __restrict__ W2,
                         const float* __restrict__ b2,
                         unsigned short* __restrict__ W2pT, float* __restrict__ v128) {
  __shared__ float s1s[128], t1s[128];
  int tid = threadIdx.x;
  if (tid < 128) {
    float mean = stat1[tid] * (1.0f / NE);
    float var = stat1[128 + tid] * (1.0f / NE) - mean * mean;
    float rstd = rsqrtf(var + 1e-5f);
    float s = g1[tid] * rstd;
    s1s[tid] = s; t1s[tid] = be1[tid] - mean * s;
  }
  __syncthreads();
  for (int i = tid; i < 16384; i += 256) {
    int n = i >> 7, k = i & 127;
    W2pT[i] = f2bf(s1s[k] * W2[k * 128 + n]);   // W2pT[n][k] = s1[k]*W2[k][n]
  }
  if (tid < 128) {
    float a = b2[tid];
    for (int k = 0; k < 128; k++) a += t1s[k] * W2[k * 128 + tid];
    v128[tid] = a;                               // v = t1@W2 + b2
  }
}

// ---------------------------------------------------------------- K3: node pass
// agg = S@W2' + cnt*v ; h2 = leaky([x,agg]@W3 + b3); BN2 stats; store h2 bf16
__global__ __launch_bounds__(256, 2) void k3_node(
    const float* __restrict__ x, const float* __restrict__ S, const float* __restrict__ cnt,
    const unsigned short* __restrict__ W2pT, const float* __restrict__ v128,
    const unsigned short* __restrict__ W3bT, const float* __restrict__ b3,
    unsigned short* __restrict__ tOut, float* __restrict__ stat2) {
  __shared__ unsigned short Abuf[128][136];   // S tile, then reused for AGG bf16
  __shared__ unsigned short Xbuf[128][72];    // x tile (64 k + 8 pad)
  __shared__ float cbuf[128];
  __shared__ float sred[256];

  const int tid = threadIdx.x;
  const int wave = tid >> 6, lane = tid & 63;
  const int l15 = lane & 15, quad = lane >> 4;
  const int rowbase = (wave >> 1) * 64;
  const int colbase = (wave & 1) * 64;

  float vj[4], b3j[4];
#pragma unroll
  for (int ct = 0; ct < 4; ct++) {
    int jc = colbase + ct * 16 + l15;
    vj[ct] = v128[jc]; b3j[ct] = b3[jc];
  }
  float lsum[4] = {0, 0, 0, 0}, lsq[4] = {0, 0, 0, 0};

  for (int t = blockIdx.x; t < NTILE_N; t += gridDim.x) {
    const int nb = t * 128;
    __syncthreads();
#pragma unroll
    for (int i = 0; i < 16; i++) {   // S tile: 128 x 128 f32 -> bf16
      int idx = tid + i * 256; int e = idx >> 5, c = idx & 31;
      int node = nb + e;
      float4 v = {0.f, 0.f, 0.f, 0.f};
      if (node < NN) v = ((const float4*)S)[(size_t)node * 32 + c];
      pack4(v, &Abuf[e][c * 4]);
    }
#pragma unroll
    for (int i = 0; i < 8; i++) {    // x tile: 128 x 64 f32 -> bf16
      int idx = tid + i * 256; int e = idx >> 4, c = idx & 15;
      int node = nb + e;
      float4 v = {0.f, 0.f, 0.f, 0.f};
      if (node < NN) v = ((const float4*)x)[(size_t)node * 16 + c];
      pack4(v, &Xbuf[e][c * 4]);
    }
    if (tid < 128) cbuf[tid] = (nb + tid < NN) ? cnt[nb + tid] : 0.0f;
    __syncthreads();

    // GEMM1: AGG = S @ W2'  (K=128)
    f32x4 acc[4][4];
#pragma unroll
    for (int rt = 0; rt < 4; rt++)
#pragma unroll
      for (int ct = 0; ct < 4; ct++) acc[rt][ct] = (f32x4){0.f, 0.f, 0.f, 0.f};
#pragma unroll
    for (int ks = 0; ks < 4; ks++) {
      s16x8 af[4];
#pragma unroll
      for (int rt = 0; rt < 4; rt++)
        af[rt] = *(const s16x8*)&Abuf[rowbase + rt * 16 + l15][ks * 32 + quad * 8];
      s16x8 bfr[4];
#pragma unroll
      for (int ct = 0; ct < 4; ct++)
        bfr[ct] = *(const s16x8*)(W2pT + (colbase + ct * 16 + l15) * 128 + ks * 32 + quad * 8);
#pragma unroll
      for (int rt = 0; rt < 4; rt++)
#pragma unroll
        for (int ct = 0; ct < 4; ct++)
          acc[rt][ct] = __builtin_amdgcn_mfma_f32_16x16x32_bf16(af[rt], bfr[ct], acc[rt][ct], 0, 0, 0);
    }
    __syncthreads();   // all waves done reading S tile; overwrite with AGG (bf16, A-layout)
#pragma unroll
    for (int rt = 0; rt < 4; rt++)
#pragma unroll
      for (int r = 0; r < 4; r++) {
        int er = rowbase + rt * 16 + quad * 4 + r;
#pragma unroll
        for (int ct = 0; ct < 4; ct++) {
          float val = acc[rt][ct][r] + cbuf[er] * vj[ct];
          Abuf[er][colbase + ct * 16 + l15] = f2bf(val);
        }
      }
    __syncthreads();

    // GEMM2: h2 = X@W3[0:64] + AGG@W3[64:192]  (K=192)
    f32x4 acc2[4][4];
#pragma unroll
    for (int rt = 0; rt < 4; rt++)
#pragma unroll
      for (int ct = 0; ct < 4; ct++) acc2[rt][ct] = (f32x4){0.f, 0.f, 0.f, 0.f};
#pragma unroll
    for (int ks = 0; ks < 6; ks++) {
      s16x8 af[4];
      if (ks < 2) {
#pragma unroll
        for (int rt = 0; rt < 4; rt++)
          af[rt] = *(const s16x8*)&Xbuf[rowbase + rt * 16 + l15][ks * 32 + quad * 8];
      } else {
#pragma unroll
        for (int rt = 0; rt < 4; rt++)
          af[rt] = *(const s16x8*)&Abuf[rowbase + rt * 16 + l15][(ks - 2) * 32 + quad * 8];
      }
      s16x8 bfr[4];
#pragma unroll
      for (int ct = 0; ct < 4; ct++)
        bfr[ct] = *(const s16x8*)(W3bT + (size_t)(colbase + ct * 16 + l15) * 192 + ks * 32 + quad * 8);
#pragma unroll
      for (int rt = 0; rt < 4; rt++)
#pragma unroll
        for (int ct = 0; ct < 4; ct++)
          acc2[rt][ct] = __builtin_amdgcn_mfma_f32_16x16x32_bf16(af[rt], bfr[ct], acc2[rt][ct], 0, 0, 0);
    }

    // epilogue: bias + leaky + BN2 stats + store t (bf16)
#pragma unroll
    for (int rt = 0; rt < 4; rt++)
#pragma unroll
      for (int r = 0; r < 4; r++) {
        int er = rowbase + rt * 16 + quad * 4 + r;
        int node = nb + er;
        if (node < NN) {
#pragma unroll
          for (int ct = 0; ct < 4; ct++) {
            float val = acc2[rt][ct][r] + b3j[ct];
            val = val > 0.0f ? val : 0.01f * val;
            lsum[ct] += val; lsq[ct] += val * val;
            tOut[(size_t)node * 128 + colbase + ct * 16 + l15] = f2bf(val);
          }
        }
      }
  }

  sred[tid] = 0.0f;
  __syncthreads();
#pragma unroll
  for (int ct = 0; ct < 4; ct++) {
    float s = lsum[ct], q = lsq[ct];
    s += __shfl_down(s, 32); q += __shfl_down(q, 32);
    s += __shfl_down(s, 16); q += __shfl_down(q, 16);
    if (lane < 16) {
      atomicAdd(&sred[colbase + ct * 16 + l15], s);
      atomicAdd(&sred[128 + colbase + ct * 16 + l15], q);
    }
  }
  __syncthreads();
  atomicAdd(&stat2[tid], sred[tid]);
}

// ---------------------------------------------------------------- K5: fold BN2 into W4
__global__ void k5_fold2(const float* __restrict__ stat2, const float* __restrict__ g2,
                         const float* __restrict__ be2, const float* __restrict__ W4,
                         const float* __restrict__ b4,
                         unsigned short* __restrict__ W4fT, float* __restrict__ b4f) {
  __shared__ float s2s[128], t2s[128];
  int tid = threadIdx.x;
  if (tid < 128) {
    float mean = stat2[tid] * (1.0f / NN);
    float var = stat2[128 + tid] * (1.0f / NN) - mean * mean;
    float rstd = rsqrtf(var + 1e-5f);
    float s = g2[tid] * rstd;
    s2s[tid] = s; t2s[tid] = be2[tid] - mean * s;
  }
  __syncthreads();
  for (int i = tid; i < 8192; i += 256) {
    int n = i >> 7, k = i & 127;
    W4fT[i] = f2bf(s2s[k] * W4[k * 64 + n]);   // W4fT[n][k], n<64
  }
  if (tid < 64) {
    float a = b4[tid];
    for (int k = 0; k < 128; k++) a += t2s[k] * W4[k * 64 + tid];
    b4f[tid] = a;
  }
}

// ---------------------------------------------------------------- K6: out = t @ W4f + b4f
__global__ __launch_bounds__(256, 2) void k6_out(
    const unsigned short* __restrict__ tIn, const unsigned short* __restrict__ W4fT,
    const float* __restrict__ b4f, float* __restrict__ out) {
  __shared__ unsigned short Abuf[128][136];
  const int tid = threadIdx.x;
  const int wave = tid >> 6, lane = tid & 63;
  const int l15 = lane & 15, quad = lane >> 4;
  const int rowbase = (wave >> 1) * 64;
  const int colbase = (wave & 1) * 32;   // out width 64 -> 2 col-waves of 32

  s16x8 bfrag[2][4];
#pragma unroll
  for (int ct = 0; ct < 2; ct++)
#pragma unroll
    for (int ks = 0; ks < 4; ks++)
      bfrag[ct][ks] = *(const s16x8*)(W4fT + (colbase + ct * 16 + l15) * 128 + ks * 32 + quad * 8);
  float bj[2];
#pragma unroll
  for (int ct = 0; ct < 2; ct++) bj[ct] = b4f[colbase + ct * 16 + l15];

  for (int t = blockIdx.x; t < NTILE_N; t += gridDim.x) {
    const int nb = t * 128;
    __syncthreads();
#pragma unroll
    for (int i = 0; i < 8; i++) {   // copy t tile (already bf16)
      int idx = tid + i * 256; int e = idx >> 4, c = idx & 15;
      int node = nb + e;
      s16x8 v = {0, 0, 0, 0, 0, 0, 0, 0};
      if (node < NN) v = *(const s16x8*)(tIn + (size_t)node * 128 + c * 8);
      *(s16x8*)&Abuf[e][c * 8] = v;
    }
    __syncthreads();

    f32x4 acc[4][2];
#pragma unroll
    for (int rt = 0; rt < 4; rt++)
#pragma unroll
      for (int ct = 0; ct < 2; ct++) acc[rt][ct] = (f32x4){0.f, 0.f, 0.f, 0.f};
#pragma unroll
    for (int ks = 0; ks < 4; ks++) {
      s16x8 af[4];
#pragma unroll
      for (int rt = 0; rt < 4; rt++)
        af[rt] = *(const s16x8*)&Abuf[rowbase + rt * 16 + l15][ks * 32 + quad * 8];
#pragma unroll
      for (int rt = 0; rt < 4; rt++)
#pragma unroll
        for (int ct = 0; ct < 2; ct++)
          acc[rt][ct] = __builtin_amdgcn_mfma_f32_16x16x32_bf16(af[rt], bfrag[ct][ks], acc[rt][ct], 0, 0, 0);
    }
#pragma unroll
    for (int rt = 0; rt < 4; rt++)
#pragma unroll
      for (int r = 0; r < 4; r++) {
        int er = rowbase + rt * 16 + quad * 4 + r;
        int node = nb + er;
        if (node < NN) {
#pragma unroll
          for (int ct = 0; ct < 2; ct++)
            out[(size_t)node * 64 + colbase + ct * 16 + l15] = acc[rt][ct][r] + bj[ct];
        }
      }
  }
}

// ---------------------------------------------------------------- launch
extern "C" void kernel_launch(void* const* d_in, const int* in_sizes, int n_in,
                              void* d_out, int out_size, void* d_ws, size_t ws_size,
                              hipStream_t stream) {
  (void)in_sizes; (void)n_in; (void)out_size; (void)ws_size;
  const float* x   = (const float*)d_in[0];
  const int*   ei  = (const int*)d_in[1];     // int64 in ref -> int32 from harness
  const float* ea  = (const float*)d_in[2];
  const float* W1  = (const float*)d_in[5];
  const float* b1  = (const float*)d_in[6];
  const float* g1  = (const float*)d_in[7];
  const float* be1 = (const float*)d_in[8];
  const float* W2  = (const float*)d_in[9];
  const float* b2  = (const float*)d_in[10];
  const float* W3  = (const float*)d_in[11];
  const float* b3  = (const float*)d_in[12];
  const float* g2  = (const float*)d_in[13];
  const float* be2 = (const float*)d_in[14];
  const float* W4  = (const float*)d_in[15];
  const float* b4  = (const float*)d_in[16];
  float* out = (float*)d_out;

  char* w = (char*)d_ws;
  float* S     = (float*)(w);                              // 51,200,000 B
  float* cnt   = (float*)(w + 51200000);                   //    400,384 B
  float* stat1 = (float*)(w + 51600384);                   //      1,024 B
  float* stat2 = (float*)(w + 51601408);                   //      1,024 B
  unsigned short* W1bT = (unsigned short*)(w + 51602432);  //     32,768 B
  unsigned short* W3bT = (unsigned short*)(w + 51635200);  //     49,152 B
  unsigned short* W2pT = (unsigned short*)(w + 51684352);  //     32,768 B
  float* v128  = (float*)(w + 51717120);                   //        512 B
  unsigned short* W4fT = (unsigned short*)(w + 51717632);  //     16,384 B
  float* b4f   = (float*)(w + 51734016);                   //        256 B
  unsigned short* tOut = (unsigned short*)(w + 51734272);  // 25,600,000 B
  // total ws use: ~77.4 MB

  hipMemsetAsync(d_ws, 0, 51602432, stream);   // zero S + cnt + stat1 + stat2

  k0_prep<<<160, 256, 0, stream>>>(W1, W3, W1bT, W3bT);
  k1_edge<<<512, 256, 0, stream>>>(x, ei, ea, W1bT, b1, S, cnt, stat1);
  k2_fold1<<<1, 256, 0, stream>>>(stat1, g1, be1, W2, b2, W2pT, v128);
  k3_node<<<512, 256, 0, stream>>>(x, S, cnt, W2pT, v128, W3bT, b3, tOut, stat2);
  k5_fold2<<<1, 256, 0, stream>>>(stat2, g2, be2, W4, b4, W4fT, b4f);
  k6_out<<<512, 256, 0, stream>>>(tOut, W4fT, b4f, out);
}

// Round 2
// 1222.947 us; speedup vs baseline: 1.0773x; 1.0773x over previous
//
#include <hip/hip_runtime.h>

#define NN 100000
#define NE 1600000
#define NTILE_E (NE / 128)      // 12500, exact
#define NTILE_N 782             // ceil(100000/128)

typedef __attribute__((ext_vector_type(4))) float f32x4;
typedef __attribute__((ext_vector_type(8))) short s16x8;

__device__ __forceinline__ unsigned short f2bf(float f) {
  unsigned u = __builtin_bit_cast(unsigned, f);
  u = (u + 0x7FFFu + ((u >> 16) & 1u)) >> 16;
  return (unsigned short)u;
}
__device__ __forceinline__ void pack4(float4 v, unsigned short* dst) {
  ushort4 h;
  h.x = f2bf(v.x); h.y = f2bf(v.y); h.z = f2bf(v.z); h.w = f2bf(v.w);
  *(ushort4*)dst = h;
}

// ---------------------------------------------------------------- K0: weight prep
__global__ void k0_prep(const float* __restrict__ W1, const float* __restrict__ W3,
                        unsigned short* __restrict__ W1bT, unsigned short* __restrict__ W3bT) {
  int i = blockIdx.x * 256 + threadIdx.x;
  if (i < 16384) {
    int n = i >> 7, k = i & 127;
    W1bT[i] = f2bf(W1[k * 128 + n]);
  } else if (i < 16384 + 24576) {
    int j = i - 16384;
    int n = j / 192, k = j % 192;
    W3bT[j] = f2bf(W3[k * 128 + n]);
  }
}

// ---------------------------------------------------------------- sort: histogram
__global__ void k_hist(const int* __restrict__ eidx, int* __restrict__ hist) {
  int e = blockIdx.x * 256 + threadIdx.x;
  if (e < NE) atomicAdd(&hist[eidx[NE + e]], 1);
}

// ---------------------------------------------------------------- sort: scan (1 block)
__global__ void k_scan(int* __restrict__ hist, float* __restrict__ cntF) {
  __shared__ int ssum[1024];
  const int t = threadIdx.x;
  const int base = t * 98;                       // 1024*98 = 100352 >= NN
  const int cl = (base >= NN) ? 0 : ((NN - base < 98) ? (NN - base) : 98);
  int s = 0;
  for (int i = 0; i < cl; i++) s += hist[base + i];
  ssum[t] = s;
  __syncthreads();
  for (int d = 1; d < 1024; d <<= 1) {
    int v = (t >= d) ? ssum[t - d] : 0;
    __syncthreads();
    ssum[t] += v;
    __syncthreads();
  }
  int run = (t == 0) ? 0 : ssum[t - 1];
  for (int i = 0; i < cl; i++) {
    int hv = hist[base + i];
    hist[base + i] = run;                        // exclusive offsets, in place
    cntF[base + i] = (float)hv;
    run += hv;
  }
}

// ---------------------------------------------------------------- sort: scatter
__global__ void k_scatter(const int* __restrict__ eidx, int* __restrict__ off,
                          int* __restrict__ colS, int* __restrict__ eaIdx) {
  int e = blockIdx.x * 256 + threadIdx.x;
  if (e < NE) {
    int c = eidx[NE + e];
    int p = atomicAdd(&off[c], 1);
    colS[p] = c;
    eaIdx[p] = e;
  }
}

// ---------------------------------------------------------------- K1: edge pass (sorted)
// h1 = leaky(concat(x[row], ea) @ W1 + b1); segmented reduce into S (sorted by col); BN1 stats
__global__ __launch_bounds__(256, 2) void k1_edge(
    const float* __restrict__ x, const int* __restrict__ eidx,
    const float* __restrict__ ea, const unsigned short* __restrict__ W1bT,
    const float* __restrict__ b1, const int* __restrict__ colS,
    const int* __restrict__ eaIdx,
    float* __restrict__ S, float* __restrict__ stat1) {
  __shared__ __align__(16) unsigned short At[128][136];   // 34816 B; aliased as Hs0 f32[128][68]
  __shared__ __align__(16) float Hs1[128][68];            // 34816 B
  __shared__ int rIdxS[128];
  __shared__ int eIdxS[128];
  __shared__ int colT[132];    // colT[i+1] = dest node of local row i; [0]/[129] halos
  __shared__ float sred[256];
  float (*Hs0)[68] = (float (*)[68])At;

  const int tid = threadIdx.x;
  const int wave = tid >> 6, lane = tid & 63;
  const int l15 = lane & 15, quad = lane >> 4;
  const int rowbase = (wave >> 1) * 64;
  const int colbase = (wave & 1) * 64;

  s16x8 bfrag[4][4];
#pragma unroll
  for (int ct = 0; ct < 4; ct++)
#pragma unroll
    for (int ks = 0; ks < 4; ks++)
      bfrag[ct][ks] = *(const s16x8*)(W1bT + (colbase + ct * 16 + l15) * 128 + ks * 32 + quad * 8);

  float b1j[4];
#pragma unroll
  for (int ct = 0; ct < 4; ct++) b1j[ct] = b1[colbase + ct * 16 + l15];

  float lsum[4] = {0, 0, 0, 0}, lsq[4] = {0, 0, 0, 0};

  for (int tile = blockIdx.x; tile < NTILE_E; tile += gridDim.x) {
    const int eb = tile * 128;
    __syncthreads();   // previous iteration's walk readers done
    if (tid < 128) {
      int e0 = eaIdx[eb + tid];
      eIdxS[tid] = e0;
      rIdxS[tid] = eidx[e0];
      colT[tid + 1] = colS[eb + tid];
    } else if (tid == 128) {
      colT[0] = (eb > 0) ? colS[eb - 1] : -1;
    } else if (tid == 129) {
      colT[129] = (eb + 128 < NE) ? colS[eb + 128] : -1;
    }
    __syncthreads();
#pragma unroll
    for (int i = 0; i < 8; i++) {
      int idx = tid + i * 256; int e = idx >> 4, c = idx & 15;
      float4 v = ((const float4*)x)[(size_t)rIdxS[e] * 16 + c];
      pack4(v, &At[e][c * 4]);
    }
#pragma unroll
    for (int i = 0; i < 8; i++) {
      int idx = tid + i * 256; int e = idx >> 4, c = idx & 15;
      float4 v = ((const float4*)ea)[(size_t)eIdxS[e] * 16 + c];
      pack4(v, &At[e][64 + c * 4]);
    }
    __syncthreads();

    f32x4 acc[4][4];
#pragma unroll
    for (int rt = 0; rt < 4; rt++)
#pragma unroll
      for (int ct = 0; ct < 4; ct++) acc[rt][ct] = (f32x4){0.f, 0.f, 0.f, 0.f};

#pragma unroll
    for (int ks = 0; ks < 4; ks++) {
      s16x8 af[4];
#pragma unroll
      for (int rt = 0; rt < 4; rt++)
        af[rt] = *(const s16x8*)&At[rowbase + rt * 16 + l15][ks * 32 + quad * 8];
#pragma unroll
      for (int rt = 0; rt < 4; rt++)
#pragma unroll
        for (int ct = 0; ct < 4; ct++)
          acc[rt][ct] = __builtin_amdgcn_mfma_f32_16x16x32_bf16(af[rt], bfrag[ct][ks], acc[rt][ct], 0, 0, 0);
    }

    __syncthreads();   // all MFMA reads of At done; safe to overwrite (Hs0 aliases At)
    // write post-leaky h1 (f32) to LDS: waves with colbase==0 -> Hs0, colbase==64 -> Hs1
    {
      float (*H)[68] = (wave & 1) ? Hs1 : Hs0;
#pragma unroll
      for (int rt = 0; rt < 4; rt++)
#pragma unroll
        for (int r = 0; r < 4; r++) {
          const int er = rowbase + rt * 16 + quad * 4 + r;
#pragma unroll
          for (int ct = 0; ct < 4; ct++) {
            float v = acc[rt][ct][r] + b1j[ct];
            v = v > 0.0f ? v : 0.01f * v;
            lsum[ct] += v; lsq[ct] += v * v;
            H[er][ct * 16 + l15] = v;
          }
        }
    }
    __syncthreads();

    // segmented flush: thread -> (col = tid&63, rows [r0, r0+32)); both halves
    {
      const int col = tid & 63;
      const int r0 = (tid >> 6) * 32;
#pragma unroll
      for (int h = 0; h < 2; h++) {
        float (*H)[68] = h ? Hs1 : Hs0;
        float runsum = H[r0][col];
        int runstart = r0;
        int curnode = colT[r0 + 1];
        for (int r = r0 + 1; r < r0 + 32; ++r) {
          int nd = colT[r + 1];
          float v = H[r][col];
          if (nd == curnode) { runsum += v; }
          else {
            float* p = S + (size_t)curnode * 128 + h * 64 + col;
            if (colT[runstart] != curnode) *p = runsum;   // run complete (end change observed)
            else atomicAdd(p, runsum);
            curnode = nd; runsum = v; runstart = r;
          }
        }
        float* p = S + (size_t)curnode * 128 + h * 64 + col;
        if (colT[runstart] != curnode && colT[r0 + 33] != curnode) *p = runsum;
        else atomicAdd(p, runsum);
      }
    }
  }

  sred[tid] = 0.0f;
  __syncthreads();
#pragma unroll
  for (int ct = 0; ct < 4; ct++) {
    float s = lsum[ct], q = lsq[ct];
    s += __shfl_down(s, 32); q += __shfl_down(q, 32);
    s += __shfl_down(s, 16); q += __shfl_down(q, 16);
    if (lane < 16) {
      atomicAdd(&sred[colbase + ct * 16 + l15], s);
      atomicAdd(&sred[128 + colbase + ct * 16 + l15], q);
    }
  }
  __syncthreads();
  atomicAdd(&stat1[tid], sred[tid]);
}

// ---------------------------------------------------------------- K2: fold BN1 into W2
__global__ void k2_fold1(const float* __restrict__ stat1, const float* __restrict__ g1,
                         const float* __restrict__ be1, const float* __restrict__ W2,
                         const float* __restrict__ b2,
                         unsigned short* __restrict__ W2pT, float* __restrict__ v128) {
  __shared__ float s1s[128], t1s[128];
  __shared__ float red[256];
  const int tid = threadIdx.x;
  if (tid < 128) {
    float mean = stat1[tid] * (1.0f / NE);
    float var = stat1[128 + tid] * (1.0f / NE) - mean * mean;
    float rstd = rsqrtf(var + 1e-5f);
    float s = g1[tid] * rstd;
    s1s[tid] = s; t1s[tid] = be1[tid] - mean * s;
  }
  __syncthreads();
  const int b = blockIdx.x;
  if (b < 16) {
#pragma unroll
    for (int j = 0; j < 4; j++) {
      int i = b * 1024 + j * 256 + tid;          // i indexes W2 [k][n] row-major
      int k = i >> 7, n = i & 127;
      W2pT[n * 128 + k] = f2bf(s1s[k] * W2[i]);
    }
  } else {
    int j = tid & 127, hh = tid >> 7;
    float p = 0.f;
    for (int k = hh * 64; k < hh * 64 + 64; k++) p += t1s[k] * W2[k * 128 + j];
    red[tid] = p;
    __syncthreads();
    if (tid < 128) v128[tid] = red[tid] + red[tid + 128] + b2[tid];
  }
}

// ---------------------------------------------------------------- K3: node pass
__global__ __launch_bounds__(256, 2) void k3_node(
    const float* __restrict__ x, const float* __restrict__ S, const float* __restrict__ cnt,
    const unsigned short* __restrict__ W2pT, const float* __restrict__ v128,
    const unsigned short* __restrict__ W3bT, const float* __restrict__ b3,
    unsigned short* __restrict__ tOut, float* __restrict__ stat2) {
  __shared__ unsigned short Abuf[128][136];
  __shared__ unsigned short Xbuf[128][72];
  __shared__ float cbuf[128];
  __shared__ float sred[256];

  const int tid = threadIdx.x;
  const int wave = tid >> 6, lane = tid & 63;
  const int l15 = lane & 15, quad = lane >> 4;
  const int rowbase = (wave >> 1) * 64;
  const int colbase = (wave & 1) * 64;

  float vj[4], b3j[4];
#pragma unroll
  for (int ct = 0; ct < 4; ct++) {
    int jc = colbase + ct * 16 + l15;
    vj[ct] = v128[jc]; b3j[ct] = b3[jc];
  }
  float lsum[4] = {0, 0, 0, 0}, lsq[4] = {0, 0, 0, 0};

  for (int t = blockIdx.x; t < NTILE_N; t += gridDim.x) {
    const int nb = t * 128;
    __syncthreads();
#pragma unroll
    for (int i = 0; i < 16; i++) {
      int idx = tid + i * 256; int e = idx >> 5, c = idx & 31;
      int node = nb + e;
      float4 v = {0.f, 0.f, 0.f, 0.f};
      if (node < NN) v = ((const float4*)S)[(size_t)node * 32 + c];
      pack4(v, &Abuf[e][c * 4]);
    }
#pragma unroll
    for (int i = 0; i < 8; i++) {
      int idx = tid + i * 256; int e = idx >> 4, c = idx & 15;
      int node = nb + e;
      float4 v = {0.f, 0.f, 0.f, 0.f};
      if (node < NN) v = ((const float4*)x)[(size_t)node * 16 + c];
      pack4(v, &Xbuf[e][c * 4]);
    }
    if (tid < 128) cbuf[tid] = (nb + tid < NN) ? cnt[nb + tid] : 0.0f;
    __syncthreads();

    f32x4 acc[4][4];
#pragma unroll
    for (int rt = 0; rt < 4; rt++)
#pragma unroll
      for (int ct = 0; ct < 4; ct++) acc[rt][ct] = (f32x4){0.f, 0.f, 0.f, 0.f};
#pragma unroll
    for (int ks = 0; ks < 4; ks++) {
      s16x8 af[4];
#pragma unroll
      for (int rt = 0; rt < 4; rt++)
        af[rt] = *(const s16x8*)&Abuf[rowbase + rt * 16 + l15][ks * 32 + quad * 8];
      s16x8 bfr[4];
#pragma unroll
      for (int ct = 0; ct < 4; ct++)
        bfr[ct] = *(const s16x8*)(W2pT + (colbase + ct * 16 + l15) * 128 + ks * 32 + quad * 8);
#pragma unroll
      for (int rt = 0; rt < 4; rt++)
#pragma unroll
        for (int ct = 0; ct < 4; ct++)
          acc[rt][ct] = __builtin_amdgcn_mfma_f32_16x16x32_bf16(af[rt], bfr[ct], acc[rt][ct], 0, 0, 0);
    }
    __syncthreads();
#pragma unroll
    for (int rt = 0; rt < 4; rt++)
#pragma unroll
      for (int r = 0; r < 4; r++) {
        int er = rowbase + rt * 16 + quad * 4 + r;
#pragma unroll
        for (int ct = 0; ct < 4; ct++) {
          float val = acc[rt][ct][r] + cbuf[er] * vj[ct];
          Abuf[er][colbase + ct * 16 + l15] = f2bf(val);
        }
      }
    __syncthreads();

    f32x4 acc2[4][4];
#pragma unroll
    for (int rt = 0; rt < 4; rt++)
#pragma unroll
      for (int ct = 0; ct < 4; ct++) acc2[rt][ct] = (f32x4){0.f, 0.f, 0.f, 0.f};
#pragma unroll
    for (int ks = 0; ks < 6; ks++) {
      s16x8 af[4];
      if (ks < 2) {
#pragma unroll
        for (int rt = 0; rt < 4; rt++)
          af[rt] = *(const s16x8*)&Xbuf[rowbase + rt * 16 + l15][ks * 32 + quad * 8];
      } else {
#pragma unroll
        for (int rt = 0; rt < 4; rt++)
          af[rt] = *(const s16x8*)&Abuf[rowbase + rt * 16 + l15][(ks - 2) * 32 + quad * 8];
      }
      s16x8 bfr[4];
#pragma unroll
      for (int ct = 0; ct < 4; ct++)
        bfr[ct] = *(const s16x8*)(W3bT + (size_t)(colbase + ct * 16 + l15) * 192 + ks * 32 + quad * 8);
#pragma unroll
      for (int rt = 0; rt < 4; rt++)
#pragma unroll
        for (int ct = 0; ct < 4; ct++)
          acc2[rt][ct] = __builtin_amdgcn_mfma_f32_16x16x32_bf16(af[rt], bfr[ct], acc2[rt][ct], 0, 0, 0);
    }

#pragma unroll
    for (int rt = 0; rt < 4; rt++)
#pragma unroll
      for (int r = 0; r < 4; r++) {
        int er = rowbase + rt * 16 + quad * 4 + r;
        int node = nb + er;
        if (node < NN) {
#pragma unroll
          for (int ct = 0; ct < 4; ct++) {
            float val = acc2[rt][ct][r] + b3j[ct];
            val = val > 0.0f ? val : 0.01f * val;
            lsum[ct] += val; lsq[ct] += val * val;
            tOut[(size_t)node * 128 + colbase + ct * 16 + l15] = f2bf(val);
          }
        }
      }
  }

  sred[tid] = 0.0f;
  __syncthreads();
#pragma unroll
  for (int ct = 0; ct < 4; ct++) {
    float s = lsum[ct], q = lsq[ct];
    s += __shfl_down(s, 32); q += __shfl_down(q, 32);
    s += __shfl_down(s, 16); q += __shfl_down(q, 16);
    if (lane < 16) {
      atomicAdd(&sred[colbase + ct * 16 + l15], s);
      atomicAdd(&sred[128 + colbase + ct * 16 + l15], q);
    }
  }
  __syncthreads();
  atomicAdd(&stat2[tid], sred[tid]);
}

// ---------------------------------------------------------------- K5: fold BN2 into W4
__global__ void k5_fold2(const float* __restrict__ stat2, const float* __restrict__ g2,
                         const float* __restrict__ be2, const float* __restrict__ W4,
                         const float* __restrict__ b4,
                         unsigned short* __restrict__ W4fT, float* __restrict__ b4f) {
  __shared__ float s2s[128], t2s[128];
  __shared__ float red[256];
  const int tid = threadIdx.x;
  if (tid < 128) {
    float mean = stat2[tid] * (1.0f / NN);
    float var = stat2[128 + tid] * (1.0f / NN) - mean * mean;
    float rstd = rsqrtf(var + 1e-5f);
    float s = g2[tid] * rstd;
    s2s[tid] = s; t2s[tid] = be2[tid] - mean * s;
  }
  __syncthreads();
  const int b = blockIdx.x;
  if (b < 8) {
#pragma unroll
    for (int j = 0; j < 4; j++) {
      int i = b * 1024 + j * 256 + tid;          // i indexes W4 [k][n] row-major, n<64
      int k = i >> 6, n = i & 63;
      W4fT[n * 128 + k] = f2bf(s2s[k] * W4[i]);
    }
  } else {
    int j = tid & 63, part = tid >> 6;
    float p = 0.f;
    for (int k = part * 32; k < part * 32 + 32; k++) p += t2s[k] * W4[k * 64 + j];
    red[tid] = p;
    __syncthreads();
    if (tid < 64) b4f[tid] = red[tid] + red[tid + 64] + red[tid + 128] + red[tid + 192] + b4[tid];
  }
}

// ---------------------------------------------------------------- K6: out = t @ W4f + b4f
__global__ __launch_bounds__(256, 2) void k6_out(
    const unsigned short* __restrict__ tIn, const unsigned short* __restrict__ W4fT,
    const float* __restrict__ b4f, float* __restrict__ out) {
  __shared__ unsigned short Abuf[128][136];
  const int tid = threadIdx.x;
  const int wave = tid >> 6, lane = tid & 63;
  const int l15 = lane & 15, quad = lane >> 4;
  const int rowbase = (wave >> 1) * 64;
  const int colbase = (wave & 1) * 32;

  s16x8 bfrag[2][4];
#pragma unroll
  for (int ct = 0; ct < 2; ct++)
#pragma unroll
    for (int ks = 0; ks < 4; ks++)
      bfrag[ct][ks] = *(const s16x8*)(W4fT + (colbase + ct * 16 + l15) * 128 + ks * 32 + quad * 8);
  float bj[2];
#pragma unroll
  for (int ct = 0; ct < 2; ct++) bj[ct] = b4f[colbase + ct * 16 + l15];

  for (int t = blockIdx.x; t < NTILE_N; t += gridDim.x) {
    const int nb = t * 128;
    __syncthreads();
#pragma unroll
    for (int i = 0; i < 8; i++) {
      int idx = tid + i * 256; int e = idx >> 4, c = idx & 15;
      int node = nb + e;
      s16x8 v = {0, 0, 0, 0, 0, 0, 0, 0};
      if (node < NN) v = *(const s16x8*)(tIn + (size_t)node * 128 + c * 8);
      *(s16x8*)&Abuf[e][c * 8] = v;
    }
    __syncthreads();

    f32x4 acc[4][2];
#pragma unroll
    for (int rt = 0; rt < 4; rt++)
#pragma unroll
      for (int ct = 0; ct < 2; ct++) acc[rt][ct] = (f32x4){0.f, 0.f, 0.f, 0.f};
#pragma unroll
    for (int ks = 0; ks < 4; ks++) {
      s16x8 af[4];
#pragma unroll
      for (int rt = 0; rt < 4; rt++)
        af[rt] = *(const s16x8*)&Abuf[rowbase + rt * 16 + l15][ks * 32 + quad * 8];
#pragma unroll
      for (int rt = 0; rt < 4; rt++)
#pragma unroll
        for (int ct = 0; ct < 2; ct++)
          acc[rt][ct] = __builtin_amdgcn_mfma_f32_16x16x32_bf16(af[rt], bfrag[ct][ks], acc[rt][ct], 0, 0, 0);
    }
#pragma unroll
    for (int rt = 0; rt < 4; rt++)
#pragma unroll
      for (int r = 0; r < 4; r++) {
        int er = rowbase + rt * 16 + quad * 4 + r;
        int node = nb + er;
        if (node < NN) {
#pragma unroll
          for (int ct = 0; ct < 2; ct++)
            out[(size_t)node * 64 + colbase + ct * 16 + l15] = acc[rt][ct][r] + bj[ct];
        }
      }
  }
}

// ---------------------------------------------------------------- launch
extern "C" void kernel_launch(void* const* d_in, const int* in_sizes, int n_in,
                              void* d_out, int out_size, void* d_ws, size_t ws_size,
                              hipStream_t stream) {
  (void)in_sizes; (void)n_in; (void)out_size; (void)ws_size;
  const float* x   = (const float*)d_in[0];
  const int*   ei  = (const int*)d_in[1];
  const float* ea  = (const float*)d_in[2];
  const float* W1  = (const float*)d_in[5];
  const float* b1  = (const float*)d_in[6];
  const float* g1  = (const float*)d_in[7];
  const float* be1 = (const float*)d_in[8];
  const float* W2  = (const float*)d_in[9];
  const float* b2  = (const float*)d_in[10];
  const float* W3  = (const float*)d_in[11];
  const float* b3  = (const float*)d_in[12];
  const float* g2  = (const float*)d_in[13];
  const float* be2 = (const float*)d_in[14];
  const float* W4  = (const float*)d_in[15];
  const float* b4  = (const float*)d_in[16];
  float* out = (float*)d_out;

  char* w = (char*)d_ws;
  float* S     = (float*)(w);                              // 51,200,000
  float* stat1 = (float*)(w + 51200000);                   //      1,024
  float* stat2 = (float*)(w + 51201024);                   //      1,024
  int*   hist  = (int*)  (w + 51202048);                   //    400,384  (also off[])
  float* cntF  = (float*)(w + 51602432);                   //    400,384
  unsigned short* W1bT = (unsigned short*)(w + 52002816);  //     32,768
  unsigned short* W3bT = (unsigned short*)(w + 52035584);  //     49,152
  unsigned short* W2pT = (unsigned short*)(w + 52084736);  //     32,768
  float* v128  = (float*)(w + 52117504);                   //        512
  unsigned short* W4fT = (unsigned short*)(w + 52118016);  //     16,384
  float* b4f   = (float*)(w + 52134400);                   //        256
  unsigned short* tOut = (unsigned short*)(w + 52134656);  // 25,600,000
  // colS/eaIdx (12.8 MB) alias tOut's space — lifetimes disjoint (sort+k1 vs k3+k6)
  int* colS  = (int*)(w + 52134656);                       //  6,400,000
  int* eaIdx = (int*)(w + 58534656);                       //  6,400,000
  // total ws use: 77,734,656 B

  hipMemsetAsync(d_ws, 0, 51602432, stream);   // zero S + stat1 + stat2 + hist

  k0_prep<<<160, 256, 0, stream>>>(W1, W3, W1bT, W3bT);
  k_hist<<<6250, 256, 0, stream>>>(ei, hist);
  k_scan<<<1, 1024, 0, stream>>>(hist, cntF);
  k_scatter<<<6250, 256, 0, stream>>>(ei, hist, colS, eaIdx);
  k1_edge<<<512, 256, 0, stream>>>(x, ei, ea, W1bT, b1, colS, eaIdx, S, stat1);
  k2_fold1<<<17, 256, 0, stream>>>(stat1, g1, be1, W2, b2, W2pT, v128);
  k3_node<<<512, 256, 0, stream>>>(x, S, cntF, W2pT, v128, W3bT, b3, tOut, stat2);
  k5_fold2<<<9, 256, 0, stream>>>(stat2, g2, be2, W4, b4, W4fT, b4f);
  k6_out<<<512, 256, 0, stream>>>(tOut, W4fT, b4f, out);
}